// Round 2
// baseline (872.919 us; speedup 1.0000x reference)
//
#include <hip/hip_runtime.h>
#include <hip/hip_bf16.h>

typedef __attribute__((ext_vector_type(8))) short bf16x8;
typedef __attribute__((ext_vector_type(4))) float f32x4;

#define DEV static __device__ __forceinline__

DEV float bf2f(unsigned short u) {
    unsigned int x = ((unsigned int)u) << 16;
    return __builtin_bit_cast(float, x);
}
DEV unsigned short f2bf(float f) {
    unsigned int x = __builtin_bit_cast(unsigned int, f);
    unsigned int r = x + 0x7fffu + ((x >> 16) & 1u);
    return (unsigned short)(r >> 16);
}
DEV float sigmoidf_(float x) { return 1.f / (1.f + __expf(-x)); }
DEV float siluf_(float x)    { return x / (1.f + __expf(-x)); }

DEV void llds16(const unsigned short* g, unsigned short* l) {
    __builtin_amdgcn_global_load_lds((const __attribute__((address_space(1))) void*)g,
                                     (__attribute__((address_space(3))) void*)l, 16, 0, 0);
}

// ---------------- shared bf16 MFMA mainloop ----------------
// A: M x K row-major bf16 (pre-offset to block row), lda
// Bt: N x K row-major bf16 (pre-offset to block col), ldb
// 128x128 tile; 256 threads = 4 waves (2x2), each wave 64x64 (4x4 16x16 frags).
// lds: 2 * (4096 A + 4096 B) ushorts = 32KB
DEV void mfma_loop(const unsigned short* __restrict__ A, const unsigned short* __restrict__ Bt,
                   int lda, int ldb, int K, unsigned short* lds, f32x4 acc[4][4])
{
    const int tid = threadIdx.x;
    const int lane = tid & 63;
    const int wid = tid >> 6;
    const int wm = wid >> 1, wn = wid & 1;
    const int row0 = tid >> 2,         cg0 = (tid & 3) * 8;
    const int row1 = (256 + tid) >> 2, cg1 = (tid & 3) * 8;
    const int dst0 = (tid - lane) * 8;
    const int dst1 = (256 + tid - lane) * 8;

    auto stage = [&](unsigned short* sbuf, int kt) {
        const unsigned short* gA = A + (size_t)kt * 32;
        const unsigned short* gB = Bt + (size_t)kt * 32;
        llds16(gA + (size_t)row0 * lda + cg0, sbuf + dst0);
        llds16(gA + (size_t)row1 * lda + cg1, sbuf + dst1);
        llds16(gB + (size_t)row0 * ldb + cg0, sbuf + 4096 + dst0);
        llds16(gB + (size_t)row1 * ldb + cg1, sbuf + 4096 + dst1);
    };

    const int KT = K >> 5;
    stage(lds, 0);
    __syncthreads();
    const int mr = lane & 15, kr = (lane >> 4) * 8;
    for (int kt = 0; kt < KT; ++kt) {
        unsigned short* sbuf = lds + (kt & 1) * 8192;
        if (kt + 1 < KT) stage(lds + ((kt + 1) & 1) * 8192, kt + 1);
        const unsigned short* sA = sbuf;
        const unsigned short* sB = sbuf + 4096;
        bf16x8 av[4], bv[4];
#pragma unroll
        for (int f = 0; f < 4; ++f) {
            av[f] = *(const bf16x8*)(sA + (wm * 64 + f * 16 + mr) * 32 + kr);
            bv[f] = *(const bf16x8*)(sB + (wn * 64 + f * 16 + mr) * 32 + kr);
        }
#pragma unroll
        for (int fm = 0; fm < 4; ++fm)
#pragma unroll
            for (int fn = 0; fn < 4; ++fn)
                acc[fm][fn] = __builtin_amdgcn_mfma_f32_16x16x32_bf16(av[fm], bv[fn], acc[fm][fn], 0, 0, 0);
        __syncthreads();
    }
}

// ---------------- weight transpose f32 (K,N) -> bf16 (N,K) ----------------
__global__ void k_transpose(const float* __restrict__ W, unsigned short* __restrict__ Wt, int K, int N)
{
    __shared__ float tile[32][33];
    int n0 = blockIdx.x * 32, k0 = blockIdx.y * 32;
    for (int i = threadIdx.y; i < 32; i += 8)
        tile[i][threadIdx.x] = W[(size_t)(k0 + i) * N + n0 + threadIdx.x];
    __syncthreads();
    for (int i = threadIdx.y; i < 32; i += 8)
        Wt[(size_t)(n0 + i) * K + k0 + threadIdx.x] = f2bf(tile[threadIdx.x][i]);
}

// ---------------- layer norm (f32 in -> bf16 out), row = token, D=1024 ----------------
__global__ __launch_bounds__(256) void k_ln(const float* __restrict__ x, const float* __restrict__ g,
                                            const float* __restrict__ b, unsigned short* __restrict__ o)
{
    size_t row = blockIdx.x;
    int tid = threadIdx.x;
    float4 v = ((const float4*)(x + row * 1024))[tid];
    float s = v.x + v.y + v.z + v.w;
    float sq = v.x * v.x + v.y * v.y + v.z * v.z + v.w * v.w;
#pragma unroll
    for (int off = 1; off < 64; off <<= 1) { s += __shfl_xor(s, off); sq += __shfl_xor(sq, off); }
    __shared__ float ls[4], lq[4];
    int wid = tid >> 6;
    if ((tid & 63) == 0) { ls[wid] = s; lq[wid] = sq; }
    __syncthreads();
    s = ls[0] + ls[1] + ls[2] + ls[3];
    sq = lq[0] + lq[1] + lq[2] + lq[3];
    float mean = s * (1.f / 1024.f);
    float var = sq * (1.f / 1024.f) - mean * mean;
    float rstd = rsqrtf(var + 1e-5f);
    float4 gv = ((const float4*)g)[tid];
    float4 bv = ((const float4*)b)[tid];
    ushort4 p;
    p.x = f2bf((v.x - mean) * rstd * gv.x + bv.x);
    p.y = f2bf((v.y - mean) * rstd * gv.y + bv.y);
    p.z = f2bf((v.z - mean) * rstd * gv.z + bv.z);
    p.w = f2bf((v.w - mean) * rstd * gv.w + bv.w);
    ((ushort4*)(o + row * 1024))[tid] = p;
}

// ---------------- EMA scan: 3 passes, SEG=256, NSEG=16 ----------------
#define SEG 256
#define NSEG 16

__global__ __launch_bounds__(64) void k_ema_a(const unsigned short* __restrict__ xn,
                                              const float* __restrict__ delta, const float* __restrict__ alpha,
                                              float* __restrict__ st)
{
    int d = blockIdx.x * 64 + threadIdx.x;
    int s = blockIdx.y, b = blockIdx.z;
    float q[16], h[16];
#pragma unroll
    for (int n = 0; n < 16; ++n) {
        float p = sigmoidf_(delta[d * 16 + n]);
        float a = sigmoidf_(alpha[d * 16 + n]);
        q[n] = 1.f - p * a; h[n] = 0.f;
    }
    const unsigned short* xp = xn + ((size_t)b * 4096 + (size_t)s * SEG) * 1024 + d;
    for (int l = 0; l < SEG; ++l) {
        float xv = bf2f(xp[(size_t)l * 1024]);
#pragma unroll
        for (int n = 0; n < 16; ++n) h[n] = q[n] * h[n] + xv;
    }
    float* sp = st + (size_t)(b * 1024 + d) * 16 * NSEG;
#pragma unroll
    for (int n = 0; n < 16; ++n) sp[n * NSEG + s] = h[n];
}

__global__ void k_ema_b(const float* __restrict__ delta, const float* __restrict__ alpha, float* __restrict__ st)
{
    int gid = blockIdx.x * 256 + threadIdx.x;   // (b*1024+d)*16+n, 65536 total
    int n = gid & 15, d = (gid >> 4) & 1023;
    float p = sigmoidf_(delta[d * 16 + n]);
    float a = sigmoidf_(alpha[d * 16 + n]);
    float qq = 1.f - p * a;
    float qs = qq;
#pragma unroll
    for (int i = 0; i < 8; ++i) qs *= qs;      // q^256
    float* sp = st + (size_t)gid * NSEG;
    float A_ = 0.f;
#pragma unroll
    for (int s = 0; s < NSEG; ++s) { float t = sp[s]; sp[s] = A_; A_ = qs * A_ + t; }
}

__global__ __launch_bounds__(64) void k_ema_c(const unsigned short* __restrict__ xn,
                                              const float* __restrict__ delta, const float* __restrict__ alpha,
                                              const float* __restrict__ beta_e, const float* __restrict__ gamma_e,
                                              const float* __restrict__ omega, const float* __restrict__ st,
                                              unsigned short* __restrict__ mxb)
{
    int d = blockIdx.x * 64 + threadIdx.x;
    int s = blockIdx.y, b = blockIdx.z;
    float q[16], c[16], h[16];
    const float* sp = st + (size_t)(b * 1024 + d) * 16 * NSEG;
#pragma unroll
    for (int n = 0; n < 16; ++n) {
        float p = sigmoidf_(delta[d * 16 + n]);
        float a = sigmoidf_(alpha[d * 16 + n]);
        q[n] = 1.f - p * a;
        c[n] = p * beta_e[d * 16 + n] * gamma_e[d * 16 + n] * 0.25f;
        h[n] = sp[n * NSEG + s];
    }
    float om = omega[d];
    const unsigned short* xp = xn + ((size_t)b * 4096 + (size_t)s * SEG) * 1024 + d;
    unsigned short* op = mxb + ((size_t)b * 4096 + (size_t)s * SEG) * 1024 + d;
    for (int l = 0; l < SEG; ++l) {
        float xv = bf2f(xp[(size_t)l * 1024]);
        float o = xv * om;
#pragma unroll
        for (int n = 0; n < 16; ++n) { h[n] = q[n] * h[n] + xv; o += c[n] * h[n]; }
        op[(size_t)l * 1024] = f2bf(siluf_(o));
    }
}

// ---------------- GEMM kernels ----------------
// v = silu(xn@Wv+bv), stored TRANSPOSED per chunk: vt[chunk(0..127)][vcol(0..1023)][c(0..127)]
__global__ __launch_bounds__(256) void k_gemm_v(const unsigned short* __restrict__ xn,
                                                const unsigned short* __restrict__ WvT,
                                                const float* __restrict__ bv, unsigned short* __restrict__ vt)
{
    __shared__ __align__(16) unsigned short lds[16384];
    int m0 = blockIdx.y * 128, n0 = blockIdx.x * 128;
    f32x4 acc[4][4] = {};
    mfma_loop(xn + (size_t)m0 * 1024, WvT + (size_t)n0 * 1024, 1024, 1024, 1024, lds, acc);
    int lane = threadIdx.x & 63, wid = threadIdx.x >> 6, wm = wid >> 1, wn = wid & 1;
#pragma unroll
    for (int fm = 0; fm < 4; ++fm)
#pragma unroll
        for (int fn = 0; fn < 4; ++fn) {
            int rowb = m0 + wm * 64 + fm * 16 + ((lane >> 4) << 2);
            int col = n0 + wn * 64 + fn * 16 + (lane & 15);
            float bias = bv[col];
            ushort4 p;
            p.x = f2bf(siluf_(acc[fm][fn][0] + bias));
            p.y = f2bf(siluf_(acc[fm][fn][1] + bias));
            p.z = f2bf(siluf_(acc[fm][fn][2] + bias));
            p.w = f2bf(siluf_(acc[fm][fn][3] + bias));
            size_t off = ((size_t)(rowb >> 7) * 1024 + col) * 128 + (rowb & 127);
            *(ushort4*)(vt + off) = p;
        }
}

// base = mx@Wmx+bmx split: u=sigmoid[:,0:1024](bf16), z->q,k (tile 8), r=silu (tiles 9..16), hx (tiles 17..24)
__global__ __launch_bounds__(256) void k_gemm_mx(const unsigned short* __restrict__ mx,
                                                 const unsigned short* __restrict__ WmxT,
                                                 const float* __restrict__ bmx,
                                                 const float* __restrict__ gamma_g, const float* __restrict__ beta_g,
                                                 unsigned short* __restrict__ ub, unsigned short* __restrict__ qb,
                                                 unsigned short* __restrict__ kb, unsigned short* __restrict__ rb,
                                                 unsigned short* __restrict__ hxb)
{
    __shared__ __align__(16) unsigned short lds[16384];
    int m0 = blockIdx.y * 128, n0 = blockIdx.x * 128;
    f32x4 acc[4][4] = {};
    mfma_loop(mx + (size_t)m0 * 1024, WmxT + (size_t)n0 * 1024, 1024, 1024, 1024, lds, acc);
    int lane = threadIdx.x & 63, wid = threadIdx.x >> 6, wm = wid >> 1, wn = wid & 1;
    int nt = blockIdx.x;
#pragma unroll
    for (int fm = 0; fm < 4; ++fm)
#pragma unroll
        for (int fn = 0; fn < 4; ++fn) {
            int rowb = m0 + wm * 64 + fm * 16 + ((lane >> 4) << 2);
            int col = n0 + wn * 64 + fn * 16 + (lane & 15);
            float bias = bmx[col];
#pragma unroll
            for (int j = 0; j < 4; ++j) {
                size_t row = rowb + j;
                float val = acc[fm][fn][j] + bias;
                if (nt < 8) {
                    ub[row * 1024 + col] = f2bf(sigmoidf_(val));
                } else if (nt == 8) {
                    int zc = col - 1024;
                    float z = siluf_(val);
                    float qv = (z * gamma_g[zc] + beta_g[zc]) * 0.088388347648318447f; // * Z^-0.5
                    float kv = z * gamma_g[128 + zc] + beta_g[128 + zc];
                    qb[row * 128 + zc] = f2bf(qv);
                    kb[row * 128 + zc] = f2bf(kv);
                } else if (nt < 17) {
                    rb[row * 1024 + (col - 1152)] = f2bf(siluf_(val));
                } else {
                    hxb[row * 1024 + (col - 2176)] = f2bf(val);
                }
            }
        }
}

// attention scores+softmax per (b,chunk): attn[bc][c][d] = softmax_d(q·k + rpb[127+d-c])
__global__ __launch_bounds__(256) void k_attn(const unsigned short* __restrict__ qb,
                                              const unsigned short* __restrict__ kb,
                                              const float* __restrict__ rpb, unsigned short* __restrict__ attn)
{
    // union: 32KB staging during mfma_loop, then bf16 scores 128x132 (33.8KB total)
    __shared__ __align__(16) union U { unsigned short stage[16384]; unsigned short sc[128 * 132]; } sh;
    int bc = blockIdx.x;
    size_t t0 = (size_t)bc * 128;
    f32x4 acc[4][4] = {};
    mfma_loop(qb + t0 * 128, kb + t0 * 128, 128, 128, 128, sh.stage, acc);
    int tid = threadIdx.x, lane = tid & 63, wid = tid >> 6, wm = wid >> 1, wn = wid & 1;
#pragma unroll
    for (int fm = 0; fm < 4; ++fm)
#pragma unroll
        for (int fn = 0; fn < 4; ++fn) {
            int r = wm * 64 + fm * 16 + ((lane >> 4) << 2);
            int c = wn * 64 + fn * 16 + (lane & 15);
#pragma unroll
            for (int j = 0; j < 4; ++j) sh.sc[(r + j) * 132 + c] = f2bf(acc[fm][fn][j]);
        }
    __syncthreads();
    int row = tid >> 1, half = tid & 1;
    const unsigned short* srow = sh.sc + row * 132 + half * 64;
    const float* bp = rpb + 127 - row + half * 64;
    float v[64];
    float mxv = -1e30f;
#pragma unroll
    for (int i = 0; i < 64; ++i) { float s = bf2f(srow[i]) + bp[i]; v[i] = s; mxv = fmaxf(mxv, s); }
    mxv = fmaxf(mxv, __shfl_xor(mxv, 1));
    float sum = 0.f;
#pragma unroll
    for (int i = 0; i < 64; ++i) { float e = __expf(v[i] - mxv); v[i] = e; sum += e; }
    sum += __shfl_xor(sum, 1);
    float inv = 1.f / sum;
    unsigned short* arow = attn + ((size_t)bc * 128 + row) * 128 + half * 64;
#pragma unroll
    for (int i = 0; i < 64; ++i) arow[i] = f2bf(v[i] * inv);
}

// h = attn @ vc; epilogue IN-PLACE over r: rhr <- f2bf(h * r). grid (ntile=8, 1, bc=128)
__global__ __launch_bounds__(256) void k_gemm_pv(const unsigned short* __restrict__ attn,
                                                 const unsigned short* __restrict__ vt,
                                                 unsigned short* __restrict__ rhr)
{
    __shared__ __align__(16) unsigned short lds[16384];
    int bc = blockIdx.z;
    int n0 = blockIdx.x * 128;
    f32x4 acc[4][4] = {};
    mfma_loop(attn + (size_t)bc * 16384, vt + (size_t)bc * 131072 + (size_t)n0 * 128, 128, 128, 128, lds, acc);
    int lane = threadIdx.x & 63, wid = threadIdx.x >> 6, wm = wid >> 1, wn = wid & 1;
#pragma unroll
    for (int fm = 0; fm < 4; ++fm)
#pragma unroll
        for (int fn = 0; fn < 4; ++fn) {
            int rowb = wm * 64 + fm * 16 + ((lane >> 4) << 2);
            int col = n0 + wn * 64 + fn * 16 + (lane & 15);
#pragma unroll
            for (int j = 0; j < 4; ++j) {
                size_t m = (size_t)bc * 128 + rowb + j;
                size_t off = m * 1024 + col;
                rhr[off] = f2bf(acc[fm][fn][j] * bf2f(rhr[off]));
            }
        }
}

// h2 = silu(hx + hr@Wh + bh); out = x + u*(h2 - x) -> d_out (f32)
__global__ __launch_bounds__(256) void k_gemm_out(const unsigned short* __restrict__ hr,
                                                  const unsigned short* __restrict__ WhT,
                                                  const float* __restrict__ bh,
                                                  const unsigned short* __restrict__ hxb,
                                                  const unsigned short* __restrict__ ub,
                                                  const float* __restrict__ x, float* __restrict__ outp)
{
    __shared__ __align__(16) unsigned short lds[16384];
    int m0 = blockIdx.y * 128, n0 = blockIdx.x * 128;
    f32x4 acc[4][4] = {};
    mfma_loop(hr + (size_t)m0 * 1024, WhT + (size_t)n0 * 1024, 1024, 1024, 1024, lds, acc);
    int lane = threadIdx.x & 63, wid = threadIdx.x >> 6, wm = wid >> 1, wn = wid & 1;
#pragma unroll
    for (int fm = 0; fm < 4; ++fm)
#pragma unroll
        for (int fn = 0; fn < 4; ++fn) {
            int rowb = m0 + wm * 64 + fm * 16 + ((lane >> 4) << 2);
            int col = n0 + wn * 64 + fn * 16 + (lane & 15);
            float bias = bh[col];
#pragma unroll
            for (int j = 0; j < 4; ++j) {
                size_t off = (size_t)(rowb + j) * 1024 + col;
                float g = acc[fm][fn][j] + bias + bf2f(hxb[off]);
                float h2 = siluf_(g);
                float xv = x[off];
                outp[off] = xv + bf2f(ub[off]) * (h2 - xv);
            }
        }
}

// t1 = silu(yn@W1+b1) bf16
__global__ __launch_bounds__(256) void k_ffn1(const unsigned short* __restrict__ yn,
                                              const unsigned short* __restrict__ W1T,
                                              const float* __restrict__ b1, unsigned short* __restrict__ t1)
{
    __shared__ __align__(16) unsigned short lds[16384];
    int m0 = blockIdx.y * 128, n0 = blockIdx.x * 128;
    f32x4 acc[4][4] = {};
    mfma_loop(yn + (size_t)m0 * 1024, W1T + (size_t)n0 * 1024, 1024, 1024, 1024, lds, acc);
    int lane = threadIdx.x & 63, wid = threadIdx.x >> 6, wm = wid >> 1, wn = wid & 1;
#pragma unroll
    for (int fm = 0; fm < 4; ++fm)
#pragma unroll
        for (int fn = 0; fn < 4; ++fn) {
            int rowb = m0 + wm * 64 + fm * 16 + ((lane >> 4) << 2);
            int col = n0 + wn * 64 + fn * 16 + (lane & 15);
            float bias = b1[col];
#pragma unroll
            for (int j = 0; j < 4; ++j)
                t1[(size_t)(rowb + j) * 2048 + col] = f2bf(siluf_(acc[fm][fn][j] + bias));
        }
}

// d_out += t1@W2 + b2   (in-place final residual)
__global__ __launch_bounds__(256) void k_ffn2(const unsigned short* __restrict__ t1,
                                              const unsigned short* __restrict__ W2T,
                                              const float* __restrict__ b2, float* __restrict__ outp)
{
    __shared__ __align__(16) unsigned short lds[16384];
    int m0 = blockIdx.y * 128, n0 = blockIdx.x * 128;
    f32x4 acc[4][4] = {};
    mfma_loop(t1 + (size_t)m0 * 2048, W2T + (size_t)n0 * 2048, 2048, 2048, 2048, lds, acc);
    int lane = threadIdx.x & 63, wid = threadIdx.x >> 6, wm = wid >> 1, wn = wid & 1;
#pragma unroll
    for (int fm = 0; fm < 4; ++fm)
#pragma unroll
        for (int fn = 0; fn < 4; ++fn) {
            int rowb = m0 + wm * 64 + fm * 16 + ((lane >> 4) << 2);
            int col = n0 + wn * 64 + fn * 16 + (lane & 15);
            float bias = b2[col];
#pragma unroll
            for (int j = 0; j < 4; ++j) {
                size_t off = (size_t)(rowb + j) * 1024 + col;
                outp[off] = outp[off] + acc[fm][fn][j] + bias;
            }
        }
}

extern "C" void kernel_launch(void* const* d_in, const int* in_sizes, int n_in,
                              void* d_out, int out_size, void* d_ws, size_t ws_size,
                              hipStream_t stream)
{
    (void)in_sizes; (void)n_in; (void)out_size; (void)ws_size;
    const float* x      = (const float*)d_in[0];
    const float* ln1_g  = (const float*)d_in[1];
    const float* ln1_b  = (const float*)d_in[2];
    const float* delta  = (const float*)d_in[3];
    const float* alpha  = (const float*)d_in[4];
    const float* beta_e = (const float*)d_in[5];
    const float* gamma_e= (const float*)d_in[6];
    const float* omega  = (const float*)d_in[7];
    const float* Wv     = (const float*)d_in[8];
    const float* bv     = (const float*)d_in[9];
    const float* Wmx    = (const float*)d_in[10];
    const float* bmx    = (const float*)d_in[11];
    const float* Wh     = (const float*)d_in[12];
    const float* bh     = (const float*)d_in[13];
    const float* gamma_g= (const float*)d_in[14];
    const float* beta_g = (const float*)d_in[15];
    const float* rpb    = (const float*)d_in[16];
    const float* ln2_g  = (const float*)d_in[17];
    const float* ln2_b  = (const float*)d_in[18];
    const float* W1     = (const float*)d_in[19];
    const float* b1     = (const float*)d_in[20];
    const float* W2     = (const float*)d_in[21];
    const float* b2     = (const float*)d_in[22];
    float* outp = (float*)d_out;

    // workspace layout (total 233,046,016 bytes ~= 222.3 MB)
    char* w = (char*)d_ws;
    unsigned short* xn   = (unsigned short*)(w + 0);           // 32MB bf16 (B,L,D)
    unsigned short* mxb  = (unsigned short*)(w + 33554432);    // 32MB bf16 (B,L,D)
    unsigned short* t1   = (unsigned short*)(w + 0);           // 64MB bf16 (B,L,2D), aliases xn+mxb (dead)
    unsigned short* vt   = (unsigned short*)(w + 67108864);    // 32MB bf16 (128,1024,128) transposed v
    unsigned short* ub   = (unsigned short*)(w + 100663296);   // 32MB bf16 (B,L,D)
    unsigned short* hxb  = (unsigned short*)(w + 134217728);   // 32MB bf16
    unsigned short* rb   = (unsigned short*)(w + 167772160);   // 32MB bf16; becomes hr in-place; then yn
    unsigned short* yn   = (unsigned short*)(w + 167772160);   // alias (rb/hr dead after k_gemm_out)
    unsigned short* qb   = (unsigned short*)(w + 201326592);   // 4MB bf16 (B,L,Z)
    unsigned short* kb   = (unsigned short*)(w + 205520896);   // 4MB
    unsigned short* at   = (unsigned short*)(w + 209715200);   // 4MB bf16 (128,128,128)
    float*          st   = (float*)(w + 209715200);            // 4MB f32 scan states, aliases at (dead before)
    unsigned short* WvT  = (unsigned short*)(w + 213909504);   // 2MB
    unsigned short* WmxT = (unsigned short*)(w + 216006656);   // 6.25MB
    unsigned short* WhT  = (unsigned short*)(w + 222560256);   // 2MB
    unsigned short* W1T  = (unsigned short*)(w + 224657408);   // 4MB
    unsigned short* W2T  = (unsigned short*)(w + 228851712);   // 4MB

    dim3 tb(32, 8);
    k_transpose<<<dim3(32, 32), tb, 0, stream>>>(Wv, WvT, 1024, 1024);
    k_transpose<<<dim3(100, 32), tb, 0, stream>>>(Wmx, WmxT, 1024, 3200);
    k_transpose<<<dim3(32, 32), tb, 0, stream>>>(Wh, WhT, 1024, 1024);
    k_transpose<<<dim3(64, 32), tb, 0, stream>>>(W1, W1T, 1024, 2048);
    k_transpose<<<dim3(32, 64), tb, 0, stream>>>(W2, W2T, 2048, 1024);

    k_ln<<<16384, 256, 0, stream>>>(x, ln1_g, ln1_b, xn);

    k_ema_a<<<dim3(16, NSEG, 4), 64, 0, stream>>>(xn, delta, alpha, st);
    k_ema_b<<<256, 256, 0, stream>>>(delta, alpha, st);
    k_ema_c<<<dim3(16, NSEG, 4), 64, 0, stream>>>(xn, delta, alpha, beta_e, gamma_e, omega, st, mxb);

    k_gemm_v<<<dim3(8, 128), 256, 0, stream>>>(xn, WvT, bv, vt);
    k_gemm_mx<<<dim3(25, 128), 256, 0, stream>>>(mxb, WmxT, bmx, gamma_g, beta_g, ub, qb, kb, rb, hxb);
    k_attn<<<128, 256, 0, stream>>>(qb, kb, rpb, at);
    k_gemm_pv<<<dim3(8, 1, 128), 256, 0, stream>>>(at, vt, rb);
    k_gemm_out<<<dim3(8, 128), 256, 0, stream>>>(rb, WhT, bh, hxb, ub, x, outp);
    k_ln<<<16384, 256, 0, stream>>>(outp, ln2_g, ln2_b, yn);
    k_ffn1<<<dim3(16, 128), 256, 0, stream>>>(yn, W1T, b1, t1);
    k_ffn2<<<dim3(8, 128), 256, 0, stream>>>(t1, W2T, b2, outp);
}

// Round 3
// 807.477 us; speedup vs baseline: 1.0810x; 1.0810x over previous
//
#include <hip/hip_runtime.h>
#include <hip/hip_bf16.h>

typedef __attribute__((ext_vector_type(8))) short bf16x8;
typedef __attribute__((ext_vector_type(4))) float f32x4;

#define DEV static __device__ __forceinline__

#define VMW(n) asm volatile("s_waitcnt vmcnt(" #n ")" ::: "memory")
#define BARX   asm volatile("s_barrier" ::: "memory")

DEV float bf2f(unsigned short u) {
    unsigned int x = ((unsigned int)u) << 16;
    return __builtin_bit_cast(float, x);
}
DEV unsigned short f2bf(float f) {
    unsigned int x = __builtin_bit_cast(unsigned int, f);
    unsigned int r = x + 0x7fffu + ((x >> 16) & 1u);
    return (unsigned short)(r >> 16);
}
DEV float sigmoidf_(float x) { return 1.f / (1.f + __expf(-x)); }
DEV float siluf_(float x)    { return x / (1.f + __expf(-x)); }

DEV void llds16(const unsigned short* g, unsigned short* l) {
    __builtin_amdgcn_global_load_lds((const __attribute__((address_space(1))) void*)g,
                                     (__attribute__((address_space(3))) void*)l, 16, 0, 0);
}

// ================= 256x256 8-wave 4-phase pipelined MFMA mainloop =================
// A: M x K row-major bf16 (pre-offset to block row), lda
// Bt: N x K row-major bf16 (pre-offset to block col), ldb
// 512 threads = 8 waves (2M x 4N). Wave w: rows (w>>2)*64 within each 128-row M-half,
// cols (w&3)*32 within each 128-col N-half. Per phase: one block C-quadrant, 16 MFMA.
// LDS: 2 buffers x (A 256x64 + B 256x64) bf16 = 128 KB. Swizzle: byte_in_row ^= (row&7)<<4,
// applied on the GLOBAL source (linear LDS dest, rule #21) and on ds_read.
DEV void mfma256(const unsigned short* __restrict__ A, const unsigned short* __restrict__ Bt,
                 int lda, int ldb, int KT, unsigned short* lds, f32x4 (&acc)[8][4])
{
    const int tid  = threadIdx.x;
    const int lane = tid & 63;
    const int w    = tid >> 6;
    const int wr   = (w >> 2) << 6;
    const int wc   = (w & 3) << 5;
    const int mr   = lane & 15;
    const int kq   = (lane >> 4) << 4;            // byte offset of k-subgroup (0,16,32,48)
    const int srow = tid >> 3;                    // staging row 0..63
    const int sw   = ((tid & 7) ^ (srow & 7)) << 3; // pre-swizzled source element offset

    auto stA = [&](int b, int kt, int h) {
        const unsigned short* g = A + (size_t)(h * 128 + srow) * lda + kt * 64 + sw;
        unsigned short* d = lds + b * 32768 + h * 8192 + tid * 8;
        llds16(g, d);
        llds16(g + (size_t)64 * lda, d + 4096);
    };
    auto stB = [&](int b, int kt, int h) {
        const unsigned short* g = Bt + (size_t)(h * 128 + srow) * ldb + kt * 64 + sw;
        unsigned short* d = lds + b * 32768 + 16384 + h * 8192 + tid * 8;
        llds16(g, d);
        llds16(g + (size_t)64 * ldb, d + 4096);
    };
    auto ldA = [&](int b, int r, int ks) -> bf16x8 {
        int byte = r * 128 + ((ks * 64 + kq) ^ ((r & 7) << 4));
        return *(const bf16x8*)((const char*)lds + (size_t)b * 65536 + byte);
    };
    auto ldB = [&](int b, int r, int ks) -> bf16x8 {
        int byte = r * 128 + ((ks * 64 + kq) ^ ((r & 7) << 4));
        return *(const bf16x8*)((const char*)lds + (size_t)b * 65536 + 32768 + byte);
    };

    // prologue: tile 0, order A0, B0, B1, A1
    stA(0, 0, 0); stB(0, 0, 0); stB(0, 0, 1); stA(0, 0, 1);

    bf16x8 av[4][2], bA[2][2], bB[2][2];
    for (int kt = 0; kt < KT; ++kt) {
        const int cu = kt & 1, nx = cu ^ 1;
        const bool more = (kt + 1 < KT);
        // ---- phase 0: quadrant (Mh=0, Nh=0); stage A-half0 of next ----
        if (more) { stA(nx, kt + 1, 0); VMW(6); } else VMW(4);
        BARX;
#pragma unroll
        for (int m = 0; m < 4; ++m) { av[m][0] = ldA(cu, wr + m * 16 + mr, 0); av[m][1] = ldA(cu, wr + m * 16 + mr, 1); }
#pragma unroll
        for (int n = 0; n < 2; ++n) { bA[n][0] = ldB(cu, wc + n * 16 + mr, 0); bA[n][1] = ldB(cu, wc + n * 16 + mr, 1); }
        __builtin_amdgcn_s_setprio(1);
#pragma unroll
        for (int m = 0; m < 4; ++m)
#pragma unroll
            for (int n = 0; n < 2; ++n) {
                acc[m][n] = __builtin_amdgcn_mfma_f32_16x16x32_bf16(av[m][0], bA[n][0], acc[m][n], 0, 0, 0);
                acc[m][n] = __builtin_amdgcn_mfma_f32_16x16x32_bf16(av[m][1], bA[n][1], acc[m][n], 0, 0, 0);
            }
        __builtin_amdgcn_s_setprio(0);
        BARX;
        // ---- phase 1: quadrant (0,1); stage B-half0 of next ----
        if (more) { stB(nx, kt + 1, 0); VMW(6); } else VMW(2);
        BARX;
#pragma unroll
        for (int n = 0; n < 2; ++n) { bB[n][0] = ldB(cu, 128 + wc + n * 16 + mr, 0); bB[n][1] = ldB(cu, 128 + wc + n * 16 + mr, 1); }
        __builtin_amdgcn_s_setprio(1);
#pragma unroll
        for (int m = 0; m < 4; ++m)
#pragma unroll
            for (int n = 0; n < 2; ++n) {
                acc[m][2 + n] = __builtin_amdgcn_mfma_f32_16x16x32_bf16(av[m][0], bB[n][0], acc[m][2 + n], 0, 0, 0);
                acc[m][2 + n] = __builtin_amdgcn_mfma_f32_16x16x32_bf16(av[m][1], bB[n][1], acc[m][2 + n], 0, 0, 0);
            }
        __builtin_amdgcn_s_setprio(0);
        BARX;
        // ---- phase 2: quadrant (1,0); stage B-half1 of next ----
        if (more) { stB(nx, kt + 1, 1); VMW(6); } else VMW(0);
        BARX;
#pragma unroll
        for (int m = 0; m < 4; ++m) { av[m][0] = ldA(cu, 128 + wr + m * 16 + mr, 0); av[m][1] = ldA(cu, 128 + wr + m * 16 + mr, 1); }
        __builtin_amdgcn_s_setprio(1);
#pragma unroll
        for (int m = 0; m < 4; ++m)
#pragma unroll
            for (int n = 0; n < 2; ++n) {
                acc[4 + m][n] = __builtin_amdgcn_mfma_f32_16x16x32_bf16(av[m][0], bA[n][0], acc[4 + m][n], 0, 0, 0);
                acc[4 + m][n] = __builtin_amdgcn_mfma_f32_16x16x32_bf16(av[m][1], bA[n][1], acc[4 + m][n], 0, 0, 0);
            }
        __builtin_amdgcn_s_setprio(0);
        BARX;
        // ---- phase 3: quadrant (1,1); stage A-half1 of next ----
        if (more) stA(nx, kt + 1, 1);
        __builtin_amdgcn_s_setprio(1);
#pragma unroll
        for (int m = 0; m < 4; ++m)
#pragma unroll
            for (int n = 0; n < 2; ++n) {
                acc[4 + m][2 + n] = __builtin_amdgcn_mfma_f32_16x16x32_bf16(av[m][0], bB[n][0], acc[4 + m][2 + n], 0, 0, 0);
                acc[4 + m][2 + n] = __builtin_amdgcn_mfma_f32_16x16x32_bf16(av[m][1], bB[n][1], acc[4 + m][2 + n], 0, 0, 0);
            }
        __builtin_amdgcn_s_setprio(0);
        BARX;
    }
}

// ================= legacy 128x128 loop (attn / PV only) =================
DEV void mfma_loop(const unsigned short* __restrict__ A, const unsigned short* __restrict__ Bt,
                   int lda, int ldb, int K, unsigned short* lds, f32x4 acc[4][4])
{
    const int tid = threadIdx.x;
    const int lane = tid & 63;
    const int wid = tid >> 6;
    const int wm = wid >> 1, wn = wid & 1;
    const int row0 = tid >> 2,         cg0 = (tid & 3) * 8;
    const int row1 = (256 + tid) >> 2, cg1 = (tid & 3) * 8;
    const int dst0 = (tid - lane) * 8;
    const int dst1 = (256 + tid - lane) * 8;

    auto stage = [&](unsigned short* sbuf, int kt) {
        const unsigned short* gA = A + (size_t)kt * 32;
        const unsigned short* gB = Bt + (size_t)kt * 32;
        llds16(gA + (size_t)row0 * lda + cg0, sbuf + dst0);
        llds16(gA + (size_t)row1 * lda + cg1, sbuf + dst1);
        llds16(gB + (size_t)row0 * ldb + cg0, sbuf + 4096 + dst0);
        llds16(gB + (size_t)row1 * ldb + cg1, sbuf + 4096 + dst1);
    };

    const int KT = K >> 5;
    stage(lds, 0);
    __syncthreads();
    const int mr = lane & 15, kr = (lane >> 4) * 8;
    for (int kt = 0; kt < KT; ++kt) {
        unsigned short* sbuf = lds + (kt & 1) * 8192;
        if (kt + 1 < KT) stage(lds + ((kt + 1) & 1) * 8192, kt + 1);
        const unsigned short* sA = sbuf;
        const unsigned short* sB = sbuf + 4096;
        bf16x8 av[4], bv[4];
#pragma unroll
        for (int f = 0; f < 4; ++f) {
            av[f] = *(const bf16x8*)(sA + (wm * 64 + f * 16 + mr) * 32 + kr);
            bv[f] = *(const bf16x8*)(sB + (wn * 64 + f * 16 + mr) * 32 + kr);
        }
#pragma unroll
        for (int fm = 0; fm < 4; ++fm)
#pragma unroll
            for (int fn = 0; fn < 4; ++fn)
                acc[fm][fn] = __builtin_amdgcn_mfma_f32_16x16x32_bf16(av[fm], bv[fn], acc[fm][fn], 0, 0, 0);
        __syncthreads();
    }
}

// ---------------- weight transpose f32 (K,N) -> bf16 (N,K) ----------------
__global__ void k_transpose(const float* __restrict__ W, unsigned short* __restrict__ Wt, int K, int N)
{
    __shared__ float tile[32][33];
    int n0 = blockIdx.x * 32, k0 = blockIdx.y * 32;
    for (int i = threadIdx.y; i < 32; i += 8)
        tile[i][threadIdx.x] = W[(size_t)(k0 + i) * N + n0 + threadIdx.x];
    __syncthreads();
    for (int i = threadIdx.y; i < 32; i += 8)
        Wt[(size_t)(n0 + i) * K + k0 + threadIdx.x] = f2bf(tile[threadIdx.x][i]);
}

// ---------------- layer norm (f32 in -> bf16 out), row = token, D=1024 ----------------
__global__ __launch_bounds__(256) void k_ln(const float* __restrict__ x, const float* __restrict__ g,
                                            const float* __restrict__ b, unsigned short* __restrict__ o)
{
    size_t row = blockIdx.x;
    int tid = threadIdx.x;
    float4 v = ((const float4*)(x + row * 1024))[tid];
    float s = v.x + v.y + v.z + v.w;
    float sq = v.x * v.x + v.y * v.y + v.z * v.z + v.w * v.w;
#pragma unroll
    for (int off = 1; off < 64; off <<= 1) { s += __shfl_xor(s, off); sq += __shfl_xor(sq, off); }
    __shared__ float ls[4], lq[4];
    int wid = tid >> 6;
    if ((tid & 63) == 0) { ls[wid] = s; lq[wid] = sq; }
    __syncthreads();
    s = ls[0] + ls[1] + ls[2] + ls[3];
    sq = lq[0] + lq[1] + lq[2] + lq[3];
    float mean = s * (1.f / 1024.f);
    float var = sq * (1.f / 1024.f) - mean * mean;
    float rstd = rsqrtf(var + 1e-5f);
    float4 gv = ((const float4*)g)[tid];
    float4 bv = ((const float4*)b)[tid];
    ushort4 p;
    p.x = f2bf((v.x - mean) * rstd * gv.x + bv.x);
    p.y = f2bf((v.y - mean) * rstd * gv.y + bv.y);
    p.z = f2bf((v.z - mean) * rstd * gv.z + bv.z);
    p.w = f2bf((v.w - mean) * rstd * gv.w + bv.w);
    ((ushort4*)(o + row * 1024))[tid] = p;
}

// ---------------- EMA scan: 3 passes, SEG=128, NSEG=32 ----------------
#define SEG 128
#define NSEG 32

__global__ __launch_bounds__(64) void k_ema_a(const unsigned short* __restrict__ xn,
                                              const float* __restrict__ delta, const float* __restrict__ alpha,
                                              float* __restrict__ st)
{
    int d = blockIdx.x * 64 + threadIdx.x;
    int s = blockIdx.y, b = blockIdx.z;
    float q[16], h[16];
#pragma unroll
    for (int n = 0; n < 16; ++n) {
        float p = sigmoidf_(delta[d * 16 + n]);
        float a = sigmoidf_(alpha[d * 16 + n]);
        q[n] = 1.f - p * a; h[n] = 0.f;
    }
    const unsigned short* xp = xn + ((size_t)b * 4096 + (size_t)s * SEG) * 1024 + d;
    for (int l = 0; l < SEG; ++l) {
        float xv = bf2f(xp[(size_t)l * 1024]);
#pragma unroll
        for (int n = 0; n < 16; ++n) h[n] = q[n] * h[n] + xv;
    }
    float* sp = st + (size_t)(b * 1024 + d) * 16 * NSEG;
#pragma unroll
    for (int n = 0; n < 16; ++n) sp[n * NSEG + s] = h[n];
}

__global__ void k_ema_b(const float* __restrict__ delta, const float* __restrict__ alpha, float* __restrict__ st)
{
    int gid = blockIdx.x * 256 + threadIdx.x;   // (b*1024+d)*16+n, 65536 total
    int n = gid & 15, d = (gid >> 4) & 1023;
    float p = sigmoidf_(delta[d * 16 + n]);
    float a = sigmoidf_(alpha[d * 16 + n]);
    float qq = 1.f - p * a;
    float qs = qq;
#pragma unroll
    for (int i = 0; i < 7; ++i) qs *= qs;      // q^128
    float* sp = st + (size_t)gid * NSEG;
    float A_ = 0.f;
#pragma unroll
    for (int s = 0; s < NSEG; ++s) { float t = sp[s]; sp[s] = A_; A_ = qs * A_ + t; }
}

__global__ __launch_bounds__(64) void k_ema_c(const unsigned short* __restrict__ xn,
                                              const float* __restrict__ delta, const float* __restrict__ alpha,
                                              const float* __restrict__ beta_e, const float* __restrict__ gamma_e,
                                              const float* __restrict__ omega, const float* __restrict__ st,
                                              unsigned short* __restrict__ mxb)
{
    int d = blockIdx.x * 64 + threadIdx.x;
    int s = blockIdx.y, b = blockIdx.z;
    float q[16], c[16], h[16];
    const float* sp = st + (size_t)(b * 1024 + d) * 16 * NSEG;
#pragma unroll
    for (int n = 0; n < 16; ++n) {
        float p = sigmoidf_(delta[d * 16 + n]);
        float a = sigmoidf_(alpha[d * 16 + n]);
        q[n] = 1.f - p * a;
        c[n] = p * beta_e[d * 16 + n] * gamma_e[d * 16 + n] * 0.25f;
        h[n] = sp[n * NSEG + s];
    }
    float om = omega[d];
    const unsigned short* xp = xn + ((size_t)b * 4096 + (size_t)s * SEG) * 1024 + d;
    unsigned short* op = mxb + ((size_t)b * 4096 + (size_t)s * SEG) * 1024 + d;
    for (int l = 0; l < SEG; ++l) {
        float xv = bf2f(xp[(size_t)l * 1024]);
        float o = xv * om;
#pragma unroll
        for (int n = 0; n < 16; ++n) { h[n] = q[n] * h[n] + xv; o += c[n] * h[n]; }
        op[(size_t)l * 1024] = f2bf(siluf_(o));
    }
}

// ================= 256x256 GEMM kernels =================
// v = silu(xn@Wv+bv), stored TRANSPOSED per chunk: vt[chunk][vcol][c]
__global__ __launch_bounds__(512, 2) void k_gemm_v2_v(const unsigned short* __restrict__ xn,
                                                      const unsigned short* __restrict__ WvT,
                                                      const float* __restrict__ bv, unsigned short* __restrict__ vt)
{
    __shared__ __align__(16) unsigned short lds[65536];
    int n0 = blockIdx.x * 256, m0 = blockIdx.y * 256;
    f32x4 acc[8][4] = {};
    mfma256(xn + (size_t)m0 * 1024, WvT + (size_t)n0 * 1024, 1024, 1024, 16, lds, acc);
    const int lane = threadIdx.x & 63, w = threadIdx.x >> 6;
    const int wr = (w >> 2) << 6, wc = (w & 3) << 5;
    const int rsub = (lane >> 4) << 2, csub = lane & 15;
#pragma unroll
    for (int i = 0; i < 8; ++i)
#pragma unroll
        for (int j = 0; j < 4; ++j) {
            int row = m0 + ((i >> 2) << 7) + wr + ((i & 3) << 4) + rsub;
            int col = n0 + ((j >> 1) << 7) + wc + ((j & 1) << 4) + csub;
            float bias = bv[col];
            ushort4 p;
            p.x = f2bf(siluf_(acc[i][j][0] + bias));
            p.y = f2bf(siluf_(acc[i][j][1] + bias));
            p.z = f2bf(siluf_(acc[i][j][2] + bias));
            p.w = f2bf(siluf_(acc[i][j][3] + bias));
            size_t off = ((size_t)(row >> 7) * 1024 + col) * 128 + (row & 127);
            *(ushort4*)(vt + off) = p;
        }
}

// base = mx@Wmx+bmx (N padded to 3328); split epilogue by column range
__global__ __launch_bounds__(512, 2) void k_gemm_v2_mx(const unsigned short* __restrict__ mx,
                                                       const unsigned short* __restrict__ WmxT,
                                                       const float* __restrict__ bmx,
                                                       const float* __restrict__ gamma_g, const float* __restrict__ beta_g,
                                                       unsigned short* __restrict__ ub, unsigned short* __restrict__ qb,
                                                       unsigned short* __restrict__ kb, unsigned short* __restrict__ rb,
                                                       unsigned short* __restrict__ hxb)
{
    __shared__ __align__(16) unsigned short lds[65536];
    int n0 = blockIdx.x * 256, m0 = blockIdx.y * 256;
    f32x4 acc[8][4] = {};
    mfma256(mx + (size_t)m0 * 1024, WmxT + (size_t)n0 * 1024, 1024, 1024, 16, lds, acc);
    const int lane = threadIdx.x & 63, w = threadIdx.x >> 6;
    const int wr = (w >> 2) << 6, wc = (w & 3) << 5;
    const int rsub = (lane >> 4) << 2, csub = lane & 15;
#pragma unroll
    for (int i = 0; i < 8; ++i)
#pragma unroll
        for (int j = 0; j < 4; ++j) {
            int rowb = m0 + ((i >> 2) << 7) + wr + ((i & 3) << 4) + rsub;
            int col = n0 + ((j >> 1) << 7) + wc + ((j & 1) << 4) + csub;
            if (col >= 3200) continue;
            float bias = bmx[col];
#pragma unroll
            for (int jj = 0; jj < 4; ++jj) {
                size_t row = rowb + jj;
                float val = acc[i][j][jj] + bias;
                if (col < 1024) {
                    ub[row * 1024 + col] = f2bf(sigmoidf_(val));
                } else if (col < 1152) {
                    int zc = col - 1024;
                    float z = siluf_(val);
                    float qv = (z * gamma_g[zc] + beta_g[zc]) * 0.088388347648318447f; // * Z^-0.5
                    float kv = z * gamma_g[128 + zc] + beta_g[128 + zc];
                    qb[row * 128 + zc] = f2bf(qv);
                    kb[row * 128 + zc] = f2bf(kv);
                } else if (col < 2176) {
                    rb[row * 1024 + (col - 1152)] = f2bf(siluf_(val));
                } else {
                    hxb[row * 1024 + (col - 2176)] = f2bf(val);
                }
            }
        }
}

// attention scores+softmax per (b,chunk): attn[bc][c][d] = softmax_d(q·k + rpb[127+d-c])
__global__ __launch_bounds__(256) void k_attn(const unsigned short* __restrict__ qb,
                                              const unsigned short* __restrict__ kb,
                                              const float* __restrict__ rpb, unsigned short* __restrict__ attn)
{
    __shared__ __align__(16) union U { unsigned short stage[16384]; unsigned short sc[128 * 132]; } sh;
    int bc = blockIdx.x;
    size_t t0 = (size_t)bc * 128;
    f32x4 acc[4][4] = {};
    mfma_loop(qb + t0 * 128, kb + t0 * 128, 128, 128, 128, sh.stage, acc);
    int tid = threadIdx.x, lane = tid & 63, wid = tid >> 6, wm = wid >> 1, wn = wid & 1;
#pragma unroll
    for (int fm = 0; fm < 4; ++fm)
#pragma unroll
        for (int fn = 0; fn < 4; ++fn) {
            int r = wm * 64 + fm * 16 + ((lane >> 4) << 2);
            int c = wn * 64 + fn * 16 + (lane & 15);
#pragma unroll
            for (int j = 0; j < 4; ++j) sh.sc[(r + j) * 132 + c] = f2bf(acc[fm][fn][j]);
        }
    __syncthreads();
    int row = tid >> 1, half = tid & 1;
    const unsigned short* srow = sh.sc + row * 132 + half * 64;
    const float* bp = rpb + 127 - row + half * 64;
    float v[64];
    float mxv = -1e30f;
#pragma unroll
    for (int i = 0; i < 64; ++i) { float s = bf2f(srow[i]) + bp[i]; v[i] = s; mxv = fmaxf(mxv, s); }
    mxv = fmaxf(mxv, __shfl_xor(mxv, 1));
    float sum = 0.f;
#pragma unroll
    for (int i = 0; i < 64; ++i) { float e = __expf(v[i] - mxv); v[i] = e; sum += e; }
    sum += __shfl_xor(sum, 1);
    float inv = 1.f / sum;
    unsigned short* arow = attn + ((size_t)bc * 128 + row) * 128 + half * 64;
#pragma unroll
    for (int i = 0; i < 64; ++i) arow[i] = f2bf(v[i] * inv);
}

// h = attn @ vc; epilogue IN-PLACE over r: rhr <- f2bf(h * r). grid (ntile=8, 1, bc=128)
__global__ __launch_bounds__(256) void k_gemm_pv(const unsigned short* __restrict__ attn,
                                                 const unsigned short* __restrict__ vt,
                                                 unsigned short* __restrict__ rhr)
{
    __shared__ __align__(16) unsigned short lds[16384];
    int bc = blockIdx.z;
    int n0 = blockIdx.x * 128;
    f32x4 acc[4][4] = {};
    mfma_loop(attn + (size_t)bc * 16384, vt + (size_t)bc * 131072 + (size_t)n0 * 128, 128, 128, 128, lds, acc);
    int lane = threadIdx.x & 63, wid = threadIdx.x >> 6, wm = wid >> 1, wn = wid & 1;
#pragma unroll
    for (int fm = 0; fm < 4; ++fm)
#pragma unroll
        for (int fn = 0; fn < 4; ++fn) {
            int rowb = wm * 64 + fm * 16 + ((lane >> 4) << 2);
            int col = n0 + wn * 64 + fn * 16 + (lane & 15);
#pragma unroll
            for (int j = 0; j < 4; ++j) {
                size_t m = (size_t)bc * 128 + rowb + j;
                size_t off = m * 1024 + col;
                rhr[off] = f2bf(acc[fm][fn][j] * bf2f(rhr[off]));
            }
        }
}

// h2 = silu(hx + hr@Wh + bh); out = x + u*(h2 - x) -> d_out (f32)
__global__ __launch_bounds__(512, 2) void k_gemm_v2_out(const unsigned short* __restrict__ hr,
                                                        const unsigned short* __restrict__ WhT,
                                                        const float* __restrict__ bh,
                                                        const unsigned short* __restrict__ hxb,
                                                        const unsigned short* __restrict__ ub,
                                                        const float* __restrict__ x, float* __restrict__ outp)
{
    __shared__ __align__(16) unsigned short lds[65536];
    int n0 = blockIdx.x * 256, m0 = blockIdx.y * 256;
    f32x4 acc[8][4] = {};
    mfma256(hr + (size_t)m0 * 1024, WhT + (size_t)n0 * 1024, 1024, 1024, 16, lds, acc);
    const int lane = threadIdx.x & 63, w = threadIdx.x >> 6;
    const int wr = (w >> 2) << 6, wc = (w & 3) << 5;
    const int rsub = (lane >> 4) << 2, csub = lane & 15;
#pragma unroll
    for (int i = 0; i < 8; ++i)
#pragma unroll
        for (int j = 0; j < 4; ++j) {
            int rowb = m0 + ((i >> 2) << 7) + wr + ((i & 3) << 4) + rsub;
            int col = n0 + ((j >> 1) << 7) + wc + ((j & 1) << 4) + csub;
            float bias = bh[col];
#pragma unroll
            for (int jj = 0; jj < 4; ++jj) {
                size_t off = (size_t)(rowb + jj) * 1024 + col;
                float g = acc[i][j][jj] + bias + bf2f(hxb[off]);
                float h2 = siluf_(g);
                float xv = x[off];
                outp[off] = xv + bf2f(ub[off]) * (h2 - xv);
            }
        }
}

// t1 = silu(yn@W1+b1) bf16
__global__ __launch_bounds__(512, 2) void k_ffn1_v2(const unsigned short* __restrict__ yn,
                                                    const unsigned short* __restrict__ W1T,
                                                    const float* __restrict__ b1, unsigned short* __restrict__ t1)
{
    __shared__ __align__(16) unsigned short lds[65536];
    int n0 = blockIdx.x * 256, m0 = blockIdx.y * 256;
    f32x4 acc[8][4] = {};
    mfma256(yn + (size_t)m0 * 1024, W1T + (size_t)n0 * 1024, 1024, 1024, 16, lds, acc);
    const int lane = threadIdx.x & 63, w = threadIdx.x >> 6;
    const int wr = (w >> 2) << 6, wc = (w & 3) << 5;
    const int rsub = (lane >> 4) << 2, csub = lane & 15;
#pragma unroll
    for (int i = 0; i < 8; ++i)
#pragma unroll
        for (int j = 0; j < 4; ++j) {
            int rowb = m0 + ((i >> 2) << 7) + wr + ((i & 3) << 4) + rsub;
            int col = n0 + ((j >> 1) << 7) + wc + ((j & 1) << 4) + csub;
            float bias = b1[col];
#pragma unroll
            for (int jj = 0; jj < 4; ++jj)
                t1[(size_t)(rowb + jj) * 2048 + col] = f2bf(siluf_(acc[i][j][jj] + bias));
        }
}

// d_out += t1@W2 + b2   (in-place final residual)
__global__ __launch_bounds__(512, 2) void k_ffn2_v2(const unsigned short* __restrict__ t1,
                                                    const unsigned short* __restrict__ W2T,
                                                    const float* __restrict__ b2, float* __restrict__ outp)
{
    __shared__ __align__(16) unsigned short lds[65536];
    int n0 = blockIdx.x * 256, m0 = blockIdx.y * 256;
    f32x4 acc[8][4] = {};
    mfma256(t1 + (size_t)m0 * 2048, W2T + (size_t)n0 * 2048, 2048, 2048, 32, lds, acc);
    const int lane = threadIdx.x & 63, w = threadIdx.x >> 6;
    const int wr = (w >> 2) << 6, wc = (w & 3) << 5;
    const int rsub = (lane >> 4) << 2, csub = lane & 15;
#pragma unroll
    for (int i = 0; i < 8; ++i)
#pragma unroll
        for (int j = 0; j < 4; ++j) {
            int rowb = m0 + ((i >> 2) << 7) + wr + ((i & 3) << 4) + rsub;
            int col = n0 + ((j >> 1) << 7) + wc + ((j & 1) << 4) + csub;
            float bias = b2[col];
#pragma unroll
            for (int jj = 0; jj < 4; ++jj) {
                size_t off = (size_t)(rowb + jj) * 1024 + col;
                outp[off] = outp[off] + acc[i][j][jj] + bias;
            }
        }
}

extern "C" void kernel_launch(void* const* d_in, const int* in_sizes, int n_in,
                              void* d_out, int out_size, void* d_ws, size_t ws_size,
                              hipStream_t stream)
{
    (void)in_sizes; (void)n_in; (void)out_size; (void)ws_size;
    const float* x      = (const float*)d_in[0];
    const float* ln1_g  = (const float*)d_in[1];
    const float* ln1_b  = (const float*)d_in[2];
    const float* delta  = (const float*)d_in[3];
    const float* alpha  = (const float*)d_in[4];
    const float* beta_e = (const float*)d_in[5];
    const float* gamma_e= (const float*)d_in[6];
    const float* omega  = (const float*)d_in[7];
    const float* Wv     = (const float*)d_in[8];
    const float* bv     = (const float*)d_in[9];
    const float* Wmx    = (const float*)d_in[10];
    const float* bmx    = (const float*)d_in[11];
    const float* Wh     = (const float*)d_in[12];
    const float* bh     = (const float*)d_in[13];
    const float* gamma_g= (const float*)d_in[14];
    const float* beta_g = (const float*)d_in[15];
    const float* rpb    = (const float*)d_in[16];
    const float* ln2_g  = (const float*)d_in[17];
    const float* ln2_b  = (const float*)d_in[18];
    const float* W1     = (const float*)d_in[19];
    const float* b1     = (const float*)d_in[20];
    const float* W2     = (const float*)d_in[21];
    const float* b2     = (const float*)d_in[22];
    float* outp = (float*)d_out;

    // workspace layout (max end 229,113,856 bytes < proven 233,046,016)
    char* w = (char*)d_ws;
    unsigned short* xn   = (unsigned short*)(w + 0);           // 32MB bf16 (B,L,D); dead after gemm_v
    unsigned short* at   = (unsigned short*)(w + 0);           // 4MB bf16 (128,128,128), over dead xn
    unsigned short* mxb  = (unsigned short*)(w + 33554432);    // 32MB bf16
    unsigned short* t1   = (unsigned short*)(w + 0);           // 64MB bf16, over dead at+mxb
    unsigned short* vt   = (unsigned short*)(w + 67108864);    // 32MB bf16 (128,1024,128) transposed v
    unsigned short* ub   = (unsigned short*)(w + 100663296);   // 32MB bf16
    unsigned short* hxb  = (unsigned short*)(w + 134217728);   // 32MB bf16
    unsigned short* rb   = (unsigned short*)(w + 167772160);   // 32MB bf16; becomes hr in-place; then yn
    unsigned short* yn   = (unsigned short*)(w + 167772160);   // alias
    unsigned short* qb   = (unsigned short*)(w + 201326592);   // 4MB bf16 (B,L,Z)
    unsigned short* kb   = (unsigned short*)(w + 205520896);   // 4MB
    float*          st   = (float*)(w + 201326592);            // 8MB f32 scan states, over qb+kb (dead before gemm_mx)
    unsigned short* WvT  = (unsigned short*)(w + 209715200);   // 2MB
    unsigned short* WmxT = (unsigned short*)(w + 211812352);   // 6.5MB (3328x1024 bf16, rows 3200.. = pad)
    unsigned short* WhT  = (unsigned short*)(w + 218628096);   // 2MB
    unsigned short* W1T  = (unsigned short*)(w + 220725248);   // 4MB
    unsigned short* W2T  = (unsigned short*)(w + 224919552);   // 4MB -> end 229113856

    dim3 tb(32, 8);
    k_transpose<<<dim3(32, 32), tb, 0, stream>>>(Wv, WvT, 1024, 1024);
    k_transpose<<<dim3(100, 32), tb, 0, stream>>>(Wmx, WmxT, 1024, 3200);
    k_transpose<<<dim3(32, 32), tb, 0, stream>>>(Wh, WhT, 1024, 1024);
    k_transpose<<<dim3(64, 32), tb, 0, stream>>>(W1, W1T, 1024, 2048);
    k_transpose<<<dim3(32, 64), tb, 0, stream>>>(W2, W2T, 2048, 1024);

    k_ln<<<16384, 256, 0, stream>>>(x, ln1_g, ln1_b, xn);

    k_ema_a<<<dim3(16, NSEG, 4), 64, 0, stream>>>(xn, delta, alpha, st);
    k_ema_b<<<256, 256, 0, stream>>>(delta, alpha, st);
    k_ema_c<<<dim3(16, NSEG, 4), 64, 0, stream>>>(xn, delta, alpha, beta_e, gamma_e, omega, st, mxb);

    k_gemm_v2_v<<<dim3(4, 64), 512, 0, stream>>>(xn, WvT, bv, vt);
    k_gemm_v2_mx<<<dim3(13, 64), 512, 0, stream>>>(mxb, WmxT, bmx, gamma_g, beta_g, ub, qb, kb, rb, hxb);
    k_attn<<<128, 256, 0, stream>>>(qb, kb, rpb, at);
    k_gemm_pv<<<dim3(8, 1, 128), 256, 0, stream>>>(at, vt, rb);
    k_gemm_v2_out<<<dim3(4, 64), 512, 0, stream>>>(rb, WhT, bh, hxb, ub, x, outp);
    k_ln<<<16384, 256, 0, stream>>>(outp, ln2_g, ln2_b, yn);
    k_ffn1_v2<<<dim3(8, 64), 512, 0, stream>>>(yn, W1T, b1, t1);
    k_ffn2_v2<<<dim3(4, 64), 512, 0, stream>>>(t1, W2T, b2, outp);
}

// Round 4
// 638.922 us; speedup vs baseline: 1.3662x; 1.2638x over previous
//
#include <hip/hip_runtime.h>
#include <hip/hip_bf16.h>

typedef __attribute__((ext_vector_type(8))) short bf16x8;
typedef __attribute__((ext_vector_type(4))) float f32x4;

#define DEV static __device__ __forceinline__

#define VMW(n) asm volatile("s_waitcnt vmcnt(" #n ")" ::: "memory")
#define BARX   asm volatile("s_barrier" ::: "memory")

DEV float bf2f(unsigned short u) {
    unsigned int x = ((unsigned int)u) << 16;
    return __builtin_bit_cast(float, x);
}
DEV unsigned short f2bf(float f) {
    unsigned int x = __builtin_bit_cast(unsigned int, f);
    unsigned int r = x + 0x7fffu + ((x >> 16) & 1u);
    return (unsigned short)(r >> 16);
}
DEV float sigmoidf_(float x) { return 1.f / (1.f + __expf(-x)); }
DEV float siluf_(float x)    { return x / (1.f + __expf(-x)); }

DEV void llds16(const unsigned short* g, unsigned short* l) {
    __builtin_amdgcn_global_load_lds((const __attribute__((address_space(1))) void*)g,
                                     (__attribute__((address_space(3))) void*)l, 16, 0, 0);
}

// XCD-aware block swizzle: gy must be divisible by 8. XCD k owns a contiguous
// y-chunk (gy/8 rows); within an XCD, x varies slowest (B-panel held, A-chunk streamed).
DEV void swz_xy(int& bx, int& by) {
    int gx = gridDim.x;
    int ychunk = gridDim.y >> 3;
    int n = blockIdx.y * gx + blockIdx.x;
    int idx = n >> 3;
    bx = idx / ychunk;
    by = (n & 7) * ychunk + (idx % ychunk);
}

// ================= 256x256 8-wave 4-phase pipelined MFMA mainloop =================
// A: M x K row-major bf16 (pre-offset to block row), lda
// Bt: N x K row-major bf16 (pre-offset to block col), ldb
// 512 threads = 8 waves (2M x 4N). LDS: 2 buffers x (A 256x64 + B 256x64) bf16 = 128 KB.
// Swizzle: byte_in_row ^= (row&7)<<4, applied on the GLOBAL source (linear LDS dest)
// and on the ds_read address.
DEV void mfma256(const unsigned short* __restrict__ A, const unsigned short* __restrict__ Bt,
                 int lda, int ldb, int KT, unsigned short* lds, f32x4 (&acc)[8][4])
{
    const int tid  = threadIdx.x;
    const int lane = tid & 63;
    const int w    = tid >> 6;
    const int wr   = (w >> 2) << 6;
    const int wc   = (w & 3) << 5;
    const int mr   = lane & 15;
    const int kq   = (lane >> 4) << 4;            // byte offset of k-subgroup
    const int srow = tid >> 3;                    // staging row 0..63
    const int sw   = ((tid & 7) ^ (srow & 7)) << 3; // pre-swizzled source element offset

    auto stA = [&](int b, int kt, int h) {
        const unsigned short* g = A + (size_t)(h * 128 + srow) * lda + kt * 64 + sw;
        unsigned short* d = lds + b * 32768 + h * 8192 + tid * 8;
        llds16(g, d);
        llds16(g + (size_t)64 * lda, d + 4096);
    };
    auto stB = [&](int b, int kt, int h) {
        const unsigned short* g = Bt + (size_t)(h * 128 + srow) * ldb + kt * 64 + sw;
        unsigned short* d = lds + b * 32768 + 16384 + h * 8192 + tid * 8;
        llds16(g, d);
        llds16(g + (size_t)64 * ldb, d + 4096);
    };
    auto ldA = [&](int b, int r, int ks) -> bf16x8 {
        int byte = r * 128 + ((ks * 64 + kq) ^ ((r & 7) << 4));
        return *(const bf16x8*)((const char*)lds + (size_t)b * 65536 + byte);
    };
    auto ldB = [&](int b, int r, int ks) -> bf16x8 {
        int byte = r * 128 + ((ks * 64 + kq) ^ ((r & 7) << 4));
        return *(const bf16x8*)((const char*)lds + (size_t)b * 65536 + 32768 + byte);
    };

    // prologue: tile 0, order A0, B0, B1, A1
    stA(0, 0, 0); stB(0, 0, 0); stB(0, 0, 1); stA(0, 0, 1);

    bf16x8 av[4][2], bA[2][2], bB[2][2];
    for (int kt = 0; kt < KT; ++kt) {
        const int cu = kt & 1, nx = cu ^ 1;
        const bool more = (kt + 1 < KT);
        // ---- phase 0: quadrant (0,0); stage A-half0 of next ----
        if (more) { stA(nx, kt + 1, 0); VMW(6); } else VMW(4);
        BARX;
#pragma unroll
        for (int m = 0; m < 4; ++m) { av[m][0] = ldA(cu, wr + m * 16 + mr, 0); av[m][1] = ldA(cu, wr + m * 16 + mr, 1); }
#pragma unroll
        for (int n = 0; n < 2; ++n) { bA[n][0] = ldB(cu, wc + n * 16 + mr, 0); bA[n][1] = ldB(cu, wc + n * 16 + mr, 1); }
        __builtin_amdgcn_s_setprio(1);
#pragma unroll
        for (int m = 0; m < 4; ++m)
#pragma unroll
            for (int n = 0; n < 2; ++n) {
                acc[m][n] = __builtin_amdgcn_mfma_f32_16x16x32_bf16(av[m][0], bA[n][0], acc[m][n], 0, 0, 0);
                acc[m][n] = __builtin_amdgcn_mfma_f32_16x16x32_bf16(av[m][1], bA[n][1], acc[m][n], 0, 0, 0);
            }
        __builtin_amdgcn_s_setprio(0);
        BARX;
        // ---- phase 1: quadrant (0,1); stage B-half0 of next ----
        if (more) { stB(nx, kt + 1, 0); VMW(6); } else VMW(2);
        BARX;
#pragma unroll
        for (int n = 0; n < 2; ++n) { bB[n][0] = ldB(cu, 128 + wc + n * 16 + mr, 0); bB[n][1] = ldB(cu, 128 + wc + n * 16 + mr, 1); }
        __builtin_amdgcn_s_setprio(1);
#pragma unroll
        for (int m = 0; m < 4; ++m)
#pragma unroll
            for (int n = 0; n < 2; ++n) {
                acc[m][2 + n] = __builtin_amdgcn_mfma_f32_16x16x32_bf16(av[m][0], bB[n][0], acc[m][2 + n], 0, 0, 0);
                acc[m][2 + n] = __builtin_amdgcn_mfma_f32_16x16x32_bf16(av[m][1], bB[n][1], acc[m][2 + n], 0, 0, 0);
            }
        __builtin_amdgcn_s_setprio(0);
        BARX;
        // ---- phase 2: quadrant (1,0); stage B-half1 of next ----
        if (more) { stB(nx, kt + 1, 1); VMW(6); } else VMW(0);
        BARX;
#pragma unroll
        for (int m = 0; m < 4; ++m) { av[m][0] = ldA(cu, 128 + wr + m * 16 + mr, 0); av[m][1] = ldA(cu, 128 + wr + m * 16 + mr, 1); }
        __builtin_amdgcn_s_setprio(1);
#pragma unroll
        for (int m = 0; m < 4; ++m)
#pragma unroll
            for (int n = 0; n < 2; ++n) {
                acc[4 + m][n] = __builtin_amdgcn_mfma_f32_16x16x32_bf16(av[m][0], bA[n][0], acc[4 + m][n], 0, 0, 0);
                acc[4 + m][n] = __builtin_amdgcn_mfma_f32_16x16x32_bf16(av[m][1], bA[n][1], acc[4 + m][n], 0, 0, 0);
            }
        __builtin_amdgcn_s_setprio(0);
        BARX;
        // ---- phase 3: quadrant (1,1); stage A-half1 of next ----
        if (more) stA(nx, kt + 1, 1);
        __builtin_amdgcn_s_setprio(1);
#pragma unroll
        for (int m = 0; m < 4; ++m)
#pragma unroll
            for (int n = 0; n < 2; ++n) {
                acc[4 + m][2 + n] = __builtin_amdgcn_mfma_f32_16x16x32_bf16(av[m][0], bB[n][0], acc[4 + m][2 + n], 0, 0, 0);
                acc[4 + m][2 + n] = __builtin_amdgcn_mfma_f32_16x16x32_bf16(av[m][1], bB[n][1], acc[4 + m][2 + n], 0, 0, 0);
            }
        __builtin_amdgcn_s_setprio(0);
        BARX;
    }
}

// ---- LDS-staged epilogue helpers (reuse the 128KB LDS after the mainloop) ----
// Row-major stage: LDS[row][col] bf16, byte = row*512 + ((col*2) ^ (((row>>2)&3)<<5)).
// Write pattern is bank-conflict-free (the 4 row-groups land on disjoint 8-bank groups).
template <class F>
DEV void stage_rm(unsigned short* lds, const f32x4 (&acc)[8][4], F f)
{
    const int lane = threadIdx.x & 63, w = threadIdx.x >> 6;
    const int wr = (w >> 2) << 6, wc = (w & 3) << 5;
    const int rsub = (lane >> 4) << 2, csub = lane & 15;
#pragma unroll
    for (int i = 0; i < 8; ++i)
#pragma unroll
        for (int j = 0; j < 4; ++j) {
            int rl = ((i >> 2) << 7) + wr + ((i & 3) << 4) + rsub;
            int cl = ((j >> 1) << 7) + wc + ((j & 1) << 4) + csub;
#pragma unroll
            for (int jj = 0; jj < 4; ++jj) {
                int r = rl + jj;
                *(unsigned short*)((char*)lds + r * 512 + ((cl * 2) ^ (((r >> 2) & 3) << 5))) =
                    f(acc[i][j][jj], cl);
            }
        }
}
// Column-major stage (for transposed outputs): LDS[col][row],
// byte = col*512 + ((row*2) ^ ((col&3)<<4)); one ushort4 (4 rows) per fragment.
template <class F>
DEV void stage_cm(unsigned short* lds, const f32x4 (&acc)[8][4], F f)
{
    const int lane = threadIdx.x & 63, w = threadIdx.x >> 6;
    const int wr = (w >> 2) << 6, wc = (w & 3) << 5;
    const int rsub = (lane >> 4) << 2, csub = lane & 15;
#pragma unroll
    for (int i = 0; i < 8; ++i)
#pragma unroll
        for (int j = 0; j < 4; ++j) {
            int rl = ((i >> 2) << 7) + wr + ((i & 3) << 4) + rsub;
            int cl = ((j >> 1) << 7) + wc + ((j & 1) << 4) + csub;
            ushort4 p;
            p.x = f(acc[i][j][0], cl); p.y = f(acc[i][j][1], cl);
            p.z = f(acc[i][j][2], cl); p.w = f(acc[i][j][3], cl);
            *(ushort4*)((char*)lds + cl * 512 + ((rl * 2) ^ ((cl & 3) << 4))) = p;
        }
}
DEV bf16x8 rd_rm(const unsigned short* lds, int row, int cb) {
    return *(const bf16x8*)((const char*)lds + row * 512 + ((cb * 16) ^ (((row >> 2) & 3) << 5)));
}
DEV bf16x8 rd_cm(const unsigned short* lds, int col, int rb) {
    return *(const bf16x8*)((const char*)lds + col * 512 + ((rb * 16) ^ ((col & 3) << 4)));
}

// ================= legacy 128x128 loop (attn / PV only) =================
DEV void mfma_loop(const unsigned short* __restrict__ A, const unsigned short* __restrict__ Bt,
                   int lda, int ldb, int K, unsigned short* lds, f32x4 acc[4][4])
{
    const int tid = threadIdx.x;
    const int lane = tid & 63;
    const int wid = tid >> 6;
    const int wm = wid >> 1, wn = wid & 1;
    const int row0 = tid >> 2,         cg0 = (tid & 3) * 8;
    const int row1 = (256 + tid) >> 2, cg1 = (tid & 3) * 8;
    const int dst0 = (tid - lane) * 8;
    const int dst1 = (256 + tid - lane) * 8;

    auto stage = [&](unsigned short* sbuf, int kt) {
        const unsigned short* gA = A + (size_t)kt * 32;
        const unsigned short* gB = Bt + (size_t)kt * 32;
        llds16(gA + (size_t)row0 * lda + cg0, sbuf + dst0);
        llds16(gA + (size_t)row1 * lda + cg1, sbuf + dst1);
        llds16(gB + (size_t)row0 * ldb + cg0, sbuf + 4096 + dst0);
        llds16(gB + (size_t)row1 * ldb + cg1, sbuf + 4096 + dst1);
    };

    const int KT = K >> 5;
    stage(lds, 0);
    __syncthreads();
    const int mr = lane & 15, kr = (lane >> 4) * 8;
    for (int kt = 0; kt < KT; ++kt) {
        unsigned short* sbuf = lds + (kt & 1) * 8192;
        if (kt + 1 < KT) stage(lds + ((kt + 1) & 1) * 8192, kt + 1);
        const unsigned short* sA = sbuf;
        const unsigned short* sB = sbuf + 4096;
        bf16x8 av[4], bv[4];
#pragma unroll
        for (int f = 0; f < 4; ++f) {
            av[f] = *(const bf16x8*)(sA + (wm * 64 + f * 16 + mr) * 32 + kr);
            bv[f] = *(const bf16x8*)(sB + (wn * 64 + f * 16 + mr) * 32 + kr);
        }
#pragma unroll
        for (int fm = 0; fm < 4; ++fm)
#pragma unroll
            for (int fn = 0; fn < 4; ++fn)
                acc[fm][fn] = __builtin_amdgcn_mfma_f32_16x16x32_bf16(av[fm], bv[fn], acc[fm][fn], 0, 0, 0);
        __syncthreads();
    }
}

// ---------------- weight transpose f32 (K,N) -> bf16 (N,K) ----------------
__global__ void k_transpose(const float* __restrict__ W, unsigned short* __restrict__ Wt, int K, int N)
{
    __shared__ float tile[32][33];
    int n0 = blockIdx.x * 32, k0 = blockIdx.y * 32;
    for (int i = threadIdx.y; i < 32; i += 8)
        tile[i][threadIdx.x] = W[(size_t)(k0 + i) * N + n0 + threadIdx.x];
    __syncthreads();
    for (int i = threadIdx.y; i < 32; i += 8)
        Wt[(size_t)(n0 + i) * K + k0 + threadIdx.x] = f2bf(tile[threadIdx.x][i]);
}

// ---------------- layer norm (f32 in -> bf16 out) ----------------
__global__ __launch_bounds__(256) void k_ln(const float* __restrict__ x, const float* __restrict__ g,
                                            const float* __restrict__ b, unsigned short* __restrict__ o)
{
    size_t row = blockIdx.x;
    int tid = threadIdx.x;
    float4 v = ((const float4*)(x + row * 1024))[tid];
    float s = v.x + v.y + v.z + v.w;
    float sq = v.x * v.x + v.y * v.y + v.z * v.z + v.w * v.w;
#pragma unroll
    for (int off = 1; off < 64; off <<= 1) { s += __shfl_xor(s, off); sq += __shfl_xor(sq, off); }
    __shared__ float ls[4], lq[4];
    int wid = tid >> 6;
    if ((tid & 63) == 0) { ls[wid] = s; lq[wid] = sq; }
    __syncthreads();
    s = ls[0] + ls[1] + ls[2] + ls[3];
    sq = lq[0] + lq[1] + lq[2] + lq[3];
    float mean = s * (1.f / 1024.f);
    float var = sq * (1.f / 1024.f) - mean * mean;
    float rstd = rsqrtf(var + 1e-5f);
    float4 gv = ((const float4*)g)[tid];
    float4 bv = ((const float4*)b)[tid];
    ushort4 p;
    p.x = f2bf((v.x - mean) * rstd * gv.x + bv.x);
    p.y = f2bf((v.y - mean) * rstd * gv.y + bv.y);
    p.z = f2bf((v.z - mean) * rstd * gv.z + bv.z);
    p.w = f2bf((v.w - mean) * rstd * gv.w + bv.w);
    ((ushort4*)(o + row * 1024))[tid] = p;
}

// ---------------- EMA scan: 3 passes, SEG=128, NSEG=32 ----------------
#define SEG 128
#define NSEG 32

__global__ __launch_bounds__(64) void k_ema_a(const unsigned short* __restrict__ xn,
                                              const float* __restrict__ delta, const float* __restrict__ alpha,
                                              float* __restrict__ st)
{
    int d = blockIdx.x * 64 + threadIdx.x;
    int s = blockIdx.y, b = blockIdx.z;
    float q[16], h[16];
#pragma unroll
    for (int n = 0; n < 16; ++n) {
        float p = sigmoidf_(delta[d * 16 + n]);
        float a = sigmoidf_(alpha[d * 16 + n]);
        q[n] = 1.f - p * a; h[n] = 0.f;
    }
    const unsigned short* xp = xn + ((size_t)b * 4096 + (size_t)s * SEG) * 1024 + d;
    for (int l = 0; l < SEG; ++l) {
        float xv = bf2f(xp[(size_t)l * 1024]);
#pragma unroll
        for (int n = 0; n < 16; ++n) h[n] = q[n] * h[n] + xv;
    }
    float* sp = st + (size_t)(b * 1024 + d) * 16 * NSEG;
#pragma unroll
    for (int n = 0; n < 16; ++n) sp[n * NSEG + s] = h[n];
}

__global__ void k_ema_b(const float* __restrict__ delta, const float* __restrict__ alpha, float* __restrict__ st)
{
    int gid = blockIdx.x * 256 + threadIdx.x;   // (b*1024+d)*16+n, 65536 total
    int n = gid & 15, d = (gid >> 4) & 1023;
    float p = sigmoidf_(delta[d * 16 + n]);
    float a = sigmoidf_(alpha[d * 16 + n]);
    float qq = 1.f - p * a;
    float qs = qq;
#pragma unroll
    for (int i = 0; i < 7; ++i) qs *= qs;      // q^128
    float* sp = st + (size_t)gid * NSEG;
    float A_ = 0.f;
#pragma unroll
    for (int s = 0; s < NSEG; ++s) { float t = sp[s]; sp[s] = A_; A_ = qs * A_ + t; }
}

__global__ __launch_bounds__(64) void k_ema_c(const unsigned short* __restrict__ xn,
                                              const float* __restrict__ delta, const float* __restrict__ alpha,
                                              const float* __restrict__ beta_e, const float* __restrict__ gamma_e,
                                              const float* __restrict__ omega, const float* __restrict__ st,
                                              unsigned short* __restrict__ mxb)
{
    int d = blockIdx.x * 64 + threadIdx.x;
    int s = blockIdx.y, b = blockIdx.z;
    float q[16], c[16], h[16];
    const float* sp = st + (size_t)(b * 1024 + d) * 16 * NSEG;
#pragma unroll
    for (int n = 0; n < 16; ++n) {
        float p = sigmoidf_(delta[d * 16 + n]);
        float a = sigmoidf_(alpha[d * 16 + n]);
        q[n] = 1.f - p * a;
        c[n] = p * beta_e[d * 16 + n] * gamma_e[d * 16 + n] * 0.25f;
        h[n] = sp[n * NSEG + s];
    }
    float om = omega[d];
    const unsigned short* xp = xn + ((size_t)b * 4096 + (size_t)s * SEG) * 1024 + d;
    unsigned short* op = mxb + ((size_t)b * 4096 + (size_t)s * SEG) * 1024 + d;
    for (int l = 0; l < SEG; ++l) {
        float xv = bf2f(xp[(size_t)l * 1024]);
        float o = xv * om;
#pragma unroll
        for (int n = 0; n < 16; ++n) { h[n] = q[n] * h[n] + xv; o += c[n] * h[n]; }
        op[(size_t)l * 1024] = f2bf(siluf_(o));
    }
}

// ================= 256x256 GEMM kernels =================
// v = silu(xn@Wv+bv), stored TRANSPOSED per chunk: vt[chunk][vcol][c]
__global__ __launch_bounds__(512, 2) void k_gemm_v2_v(const unsigned short* __restrict__ xn,
                                                      const unsigned short* __restrict__ WvT,
                                                      const float* __restrict__ bv, unsigned short* __restrict__ vt)
{
    __shared__ __align__(16) unsigned short lds[65536];
    int bx, by; swz_xy(bx, by);
    int n0 = bx * 256, m0 = by * 256;
    f32x4 acc[8][4] = {};
    mfma256(xn + (size_t)m0 * 1024, WvT + (size_t)n0 * 1024, 1024, 1024, 16, lds, acc);
    stage_cm(lds, acc, [&](float v, int cl) -> unsigned short {
        return f2bf(siluf_(v + bv[n0 + cl]));
    });
    __syncthreads();
    const int t = threadIdx.x;
#pragma unroll
    for (int it = 0; it < 16; ++it) {
        int col = it * 16 + (t >> 5);
        int rb = t & 31;
        bf16x8 vv = rd_cm(lds, col, rb);
        int grow = m0 + rb * 8;
        size_t off = ((size_t)(grow >> 7) * 1024 + (n0 + col)) * 128 + (grow & 127);
        *(bf16x8*)(vt + off) = vv;
    }
}

// base = mx@Wmx+bmx (N padded to 3328); activations applied pre-stage, splits at readback
__global__ __launch_bounds__(512, 2) void k_gemm_v2_mx(const unsigned short* __restrict__ mx,
                                                       const unsigned short* __restrict__ WmxT,
                                                       const float* __restrict__ bmx,
                                                       const float* __restrict__ gamma_g, const float* __restrict__ beta_g,
                                                       unsigned short* __restrict__ ub, unsigned short* __restrict__ qb,
                                                       unsigned short* __restrict__ kb, unsigned short* __restrict__ rb,
                                                       unsigned short* __restrict__ hxb)
{
    __shared__ __align__(16) unsigned short lds[65536];
    int bx, by; swz_xy(bx, by);
    int n0 = bx * 256, m0 = by * 256;
    f32x4 acc[8][4] = {};
    mfma256(mx + (size_t)m0 * 1024, WmxT + (size_t)n0 * 1024, 1024, 1024, 16, lds, acc);
    stage_rm(lds, acc, [&](float v, int cl) -> unsigned short {
        int gc = n0 + cl;
        if (gc >= 3200) return 0;
        float val = v + bmx[gc];
        if (gc < 1024) return f2bf(sigmoidf_(val));        // u
        if (gc < 2176) return f2bf(siluf_(val));           // z (1024..1151) and r (1152..2175)
        return f2bf(val);                                  // hx
    });
    __syncthreads();
    const int t = threadIdx.x;
#pragma unroll
    for (int it = 0; it < 16; ++it) {
        int row = it * 16 + (t >> 5);
        int cb = t & 31;
        int gc = n0 + cb * 8;
        if (gc >= 3200) continue;
        bf16x8 vv = rd_rm(lds, row, cb);
        size_t grow = m0 + row;
        if (gc < 1024) {
            *(bf16x8*)(ub + grow * 1024 + gc) = vv;
        } else if (gc < 1152) {
            int zc = gc - 1024;
            bf16x8 qv, kv;
#pragma unroll
            for (int e = 0; e < 8; ++e) {
                float z = bf2f((unsigned short)vv[e]);
                qv[e] = (short)f2bf((z * gamma_g[zc + e] + beta_g[zc + e]) * 0.088388347648318447f);
                kv[e] = (short)f2bf(z * gamma_g[128 + zc + e] + beta_g[128 + zc + e]);
            }
            *(bf16x8*)(qb + grow * 128 + zc) = qv;
            *(bf16x8*)(kb + grow * 128 + zc) = kv;
        } else if (gc < 2176) {
            *(bf16x8*)(rb + grow * 1024 + (gc - 1152)) = vv;
        } else {
            *(bf16x8*)(hxb + grow * 1024 + (gc - 2176)) = vv;
        }
    }
}

// attention scores+softmax per (b,chunk): attn[bc][c][d] = softmax_d(q·k + rpb[127+d-c])
__global__ __launch_bounds__(256) void k_attn(const unsigned short* __restrict__ qb,
                                              const unsigned short* __restrict__ kb,
                                              const float* __restrict__ rpb, unsigned short* __restrict__ attn)
{
    __shared__ __align__(16) union U { unsigned short stage[16384]; unsigned short sc[128 * 132]; } sh;
    int bc = blockIdx.x;
    size_t t0 = (size_t)bc * 128;
    f32x4 acc[4][4] = {};
    mfma_loop(qb + t0 * 128, kb + t0 * 128, 128, 128, 128, sh.stage, acc);
    int tid = threadIdx.x, lane = tid & 63, wid = tid >> 6, wm = wid >> 1, wn = wid & 1;
#pragma unroll
    for (int fm = 0; fm < 4; ++fm)
#pragma unroll
        for (int fn = 0; fn < 4; ++fn) {
            int r = wm * 64 + fm * 16 + ((lane >> 4) << 2);
            int c = wn * 64 + fn * 16 + (lane & 15);
#pragma unroll
            for (int j = 0; j < 4; ++j) sh.sc[(r + j) * 132 + c] = f2bf(acc[fm][fn][j]);
        }
    __syncthreads();
    int row = tid >> 1, half = tid & 1;
    const unsigned short* srow = sh.sc + row * 132 + half * 64;
    const float* bp = rpb + 127 - row + half * 64;
    float v[64];
    float mxv = -1e30f;
#pragma unroll
    for (int i = 0; i < 64; ++i) { float s = bf2f(srow[i]) + bp[i]; v[i] = s; mxv = fmaxf(mxv, s); }
    mxv = fmaxf(mxv, __shfl_xor(mxv, 1));
    float sum = 0.f;
#pragma unroll
    for (int i = 0; i < 64; ++i) { float e = __expf(v[i] - mxv); v[i] = e; sum += e; }
    sum += __shfl_xor(sum, 1);
    float inv = 1.f / sum;
    unsigned short* arow = attn + ((size_t)bc * 128 + row) * 128 + half * 64;
#pragma unroll
    for (int i = 0; i < 64; ++i) arow[i] = f2bf(v[i] * inv);
}

// h = attn @ vc; epilogue IN-PLACE over r: rhr <- f2bf(h * r). grid (ntile=8, 1, bc=128)
__global__ __launch_bounds__(256) void k_gemm_pv(const unsigned short* __restrict__ attn,
                                                 const unsigned short* __restrict__ vt,
                                                 unsigned short* __restrict__ rhr)
{
    __shared__ __align__(16) unsigned short lds[16384];
    int bc = blockIdx.z;
    int n0 = blockIdx.x * 128;
    f32x4 acc[4][4] = {};
    mfma_loop(attn + (size_t)bc * 16384, vt + (size_t)bc * 131072 + (size_t)n0 * 128, 128, 128, 128, lds, acc);
    int lane = threadIdx.x & 63, wid = threadIdx.x >> 6, wm = wid >> 1, wn = wid & 1;
#pragma unroll
    for (int fm = 0; fm < 4; ++fm)
#pragma unroll
        for (int fn = 0; fn < 4; ++fn) {
            int rowb = wm * 64 + fm * 16 + ((lane >> 4) << 2);
            int col = n0 + wn * 64 + fn * 16 + (lane & 15);
#pragma unroll
            for (int j = 0; j < 4; ++j) {
                size_t m = (size_t)bc * 128 + rowb + j;
                size_t off = m * 1024 + col;
                rhr[off] = f2bf(acc[fm][fn][j] * bf2f(rhr[off]));
            }
        }
}

// h2 = silu(hx + hr@Wh + bh); out = x + u*(h2 - x) -> d_out (f32). Full-line f32 stores per wave.
__global__ __launch_bounds__(512, 2) void k_gemm_v2_out(const unsigned short* __restrict__ hr,
                                                        const unsigned short* __restrict__ WhT,
                                                        const float* __restrict__ bh,
                                                        const unsigned short* __restrict__ hxb,
                                                        const unsigned short* __restrict__ ub,
                                                        const float* __restrict__ x, float* __restrict__ outp)
{
    __shared__ __align__(16) unsigned short lds[65536];
    int bx, by; swz_xy(bx, by);
    int n0 = bx * 256, m0 = by * 256;
    f32x4 acc[8][4] = {};
    mfma256(hr + (size_t)m0 * 1024, WhT + (size_t)n0 * 1024, 1024, 1024, 16, lds, acc);
    const int lane = threadIdx.x & 63, w = threadIdx.x >> 6;
    const int wr = (w >> 2) << 6, wc = (w & 3) << 5;
    const int rsub = (lane >> 4) << 2, csub = lane & 15;
#pragma unroll
    for (int i = 0; i < 8; ++i)
#pragma unroll
        for (int j = 0; j < 4; ++j) {
            int rowb = m0 + ((i >> 2) << 7) + wr + ((i & 3) << 4) + rsub;
            int col = n0 + ((j >> 1) << 7) + wc + ((j & 1) << 4) + csub;
            float bias = bh[col];
#pragma unroll
            for (int jj = 0; jj < 4; ++jj) {
                size_t off = (size_t)(rowb + jj) * 1024 + col;
                float g = acc[i][j][jj] + bias + bf2f(hxb[off]);
                float h2 = siluf_(g);
                float xv = x[off];
                outp[off] = xv + bf2f(ub[off]) * (h2 - xv);
            }
        }
}

// t1 = silu(yn@W1+b1) bf16, LDS-staged epilogue
__global__ __launch_bounds__(512, 2) void k_ffn1_v2(const unsigned short* __restrict__ yn,
                                                    const unsigned short* __restrict__ W1T,
                                                    const float* __restrict__ b1, unsigned short* __restrict__ t1)
{
    __shared__ __align__(16) unsigned short lds[65536];
    int bx, by; swz_xy(bx, by);
    int n0 = bx * 256, m0 = by * 256;
    f32x4 acc[8][4] = {};
    mfma256(yn + (size_t)m0 * 1024, W1T + (size_t)n0 * 1024, 1024, 1024, 16, lds, acc);
    stage_rm(lds, acc, [&](float v, int cl) -> unsigned short {
        return f2bf(siluf_(v + b1[n0 + cl]));
    });
    __syncthreads();
    const int t = threadIdx.x;
#pragma unroll
    for (int it = 0; it < 16; ++it) {
        int row = it * 16 + (t >> 5);
        int cb = t & 31;
        bf16x8 vv = rd_rm(lds, row, cb);
        *(bf16x8*)(t1 + (size_t)(m0 + row) * 2048 + n0 + cb * 8) = vv;
    }
}

// d_out += t1@W2 + b2   (in-place final residual; full-line f32 stores per wave)
__global__ __launch_bounds__(512, 2) void k_ffn2_v2(const unsigned short* __restrict__ t1,
                                                    const unsigned short* __restrict__ W2T,
                                                    const float* __restrict__ b2, float* __restrict__ outp)
{
    __shared__ __align__(16) unsigned short lds[65536];
    int bx, by; swz_xy(bx, by);
    int n0 = bx * 256, m0 = by * 256;
    f32x4 acc[8][4] = {};
    mfma256(t1 + (size_t)m0 * 2048, W2T + (size_t)n0 * 2048, 2048, 2048, 32, lds, acc);
    const int lane = threadIdx.x & 63, w = threadIdx.x >> 6;
    const int wr = (w >> 2) << 6, wc = (w & 3) << 5;
    const int rsub = (lane >> 4) << 2, csub = lane & 15;
#pragma unroll
    for (int i = 0; i < 8; ++i)
#pragma unroll
        for (int j = 0; j < 4; ++j) {
            int rowb = m0 + ((i >> 2) << 7) + wr + ((i & 3) << 4) + rsub;
            int col = n0 + ((j >> 1) << 7) + wc + ((j & 1) << 4) + csub;
            float bias = b2[col];
#pragma unroll
            for (int jj = 0; jj < 4; ++jj) {
                size_t off = (size_t)(rowb + jj) * 1024 + col;
                outp[off] = outp[off] + acc[i][j][jj] + bias;
            }
        }
}

extern "C" void kernel_launch(void* const* d_in, const int* in_sizes, int n_in,
                              void* d_out, int out_size, void* d_ws, size_t ws_size,
                              hipStream_t stream)
{
    (void)in_sizes; (void)n_in; (void)out_size; (void)ws_size;
    const float* x      = (const float*)d_in[0];
    const float* ln1_g  = (const float*)d_in[1];
    const float* ln1_b  = (const float*)d_in[2];
    const float* delta  = (const float*)d_in[3];
    const float* alpha  = (const float*)d_in[4];
    const float* beta_e = (const float*)d_in[5];
    const float* gamma_e= (const float*)d_in[6];
    const float* omega  = (const float*)d_in[7];
    const float* Wv     = (const float*)d_in[8];
    const float* bv     = (const float*)d_in[9];
    const float* Wmx    = (const float*)d_in[10];
    const float* bmx    = (const float*)d_in[11];
    const float* Wh     = (const float*)d_in[12];
    const float* bh     = (const float*)d_in[13];
    const float* gamma_g= (const float*)d_in[14];
    const float* beta_g = (const float*)d_in[15];
    const float* rpb    = (const float*)d_in[16];
    const float* ln2_g  = (const float*)d_in[17];
    const float* ln2_b  = (const float*)d_in[18];
    const float* W1     = (const float*)d_in[19];
    const float* b1     = (const float*)d_in[20];
    const float* W2     = (const float*)d_in[21];
    const float* b2     = (const float*)d_in[22];
    float* outp = (float*)d_out;

    // workspace layout (max end 229,113,856 bytes)
    char* w = (char*)d_ws;
    unsigned short* xn   = (unsigned short*)(w + 0);           // 32MB bf16 (B,L,D); dead after gemm_v
    unsigned short* at   = (unsigned short*)(w + 0);           // 4MB bf16 (128,128,128), over dead xn
    unsigned short* mxb  = (unsigned short*)(w + 33554432);    // 32MB bf16
    unsigned short* t1   = (unsigned short*)(w + 0);           // 64MB bf16, over dead at+mxb
    unsigned short* vt   = (unsigned short*)(w + 67108864);    // 32MB bf16 (128,1024,128) transposed v
    unsigned short* ub   = (unsigned short*)(w + 100663296);   // 32MB bf16
    unsigned short* hxb  = (unsigned short*)(w + 134217728);   // 32MB bf16
    unsigned short* rb   = (unsigned short*)(w + 167772160);   // 32MB bf16; becomes hr in-place; then yn
    unsigned short* yn   = (unsigned short*)(w + 167772160);   // alias
    unsigned short* qb   = (unsigned short*)(w + 201326592);   // 4MB bf16 (B,L,Z)
    unsigned short* kb   = (unsigned short*)(w + 205520896);   // 4MB
    float*          st   = (float*)(w + 201326592);            // 8MB f32 scan states, over qb+kb (dead before gemm_mx)
    unsigned short* WvT  = (unsigned short*)(w + 209715200);   // 2MB
    unsigned short* WmxT = (unsigned short*)(w + 211812352);   // 6.5MB (3328x1024 bf16, rows 3200.. = pad)
    unsigned short* WhT  = (unsigned short*)(w + 218628096);   // 2MB
    unsigned short* W1T  = (unsigned short*)(w + 220725248);   // 4MB
    unsigned short* W2T  = (unsigned short*)(w + 224919552);   // 4MB -> end 229113856

    dim3 tb(32, 8);
    k_transpose<<<dim3(32, 32), tb, 0, stream>>>(Wv, WvT, 1024, 1024);
    k_transpose<<<dim3(100, 32), tb, 0, stream>>>(Wmx, WmxT, 1024, 3200);
    k_transpose<<<dim3(32, 32), tb, 0, stream>>>(Wh, WhT, 1024, 1024);
    k_transpose<<<dim3(64, 32), tb, 0, stream>>>(W1, W1T, 1024, 2048);
    k_transpose<<<dim3(32, 64), tb, 0, stream>>>(W2, W2T, 2048, 1024);

    k_ln<<<16384, 256, 0, stream>>>(x, ln1_g, ln1_b, xn);

    k_ema_a<<<dim3(16, NSEG, 4), 64, 0, stream>>>(xn, delta, alpha, st);
    k_ema_b<<<256, 256, 0, stream>>>(delta, alpha, st);
    k_ema_c<<<dim3(16, NSEG, 4), 64, 0, stream>>>(xn, delta, alpha, beta_e, gamma_e, omega, st, mxb);

    k_gemm_v2_v<<<dim3(4, 64), 512, 0, stream>>>(xn, WvT, bv, vt);
    k_gemm_v2_mx<<<dim3(13, 64), 512, 0, stream>>>(mxb, WmxT, bmx, gamma_g, beta_g, ub, qb, kb, rb, hxb);
    k_attn<<<128, 256, 0, stream>>>(qb, kb, rpb, at);
    k_gemm_pv<<<dim3(8, 1, 128), 256, 0, stream>>>(at, vt, rb);
    k_gemm_v2_out<<<dim3(4, 64), 512, 0, stream>>>(rb, WhT, bh, hxb, ub, x, outp);
    k_ln<<<16384, 256, 0, stream>>>(outp, ln2_g, ln2_b, yn);
    k_ffn1_v2<<<dim3(8, 64), 512, 0, stream>>>(yn, W1T, b1, t1);
    k_ffn2_v2<<<dim3(4, 64), 512, 0, stream>>>(t1, W2T, b2, outp);
}